// Round 3
// baseline (1539.699 us; speedup 1.0000x reference)
//
#include <hip/hip_runtime.h>

#define D 64
#define LN_EPS 1e-5f
#define ALPHA 0.5f

#define GB 64            // nodes per bucket
#define GSH 6            // log2(GB)
#define CAP 2048         // bucket capacity (mean ~1535, sigma ~39 -> 13 sigma slack)

// ---------------- Stage 1: WzUx = nf * (z@W.T + deg*(x@U.T + Ub)) ----------
__global__ __launch_bounds__(256) void wzux_kernel(
    const float* __restrict__ z, const float* __restrict__ x,
    const float* __restrict__ nf, const float* __restrict__ W,
    const float* __restrict__ Uw, const float* __restrict__ Ub,
    float* __restrict__ wzux, int N)
{
    __shared__ float Wsm[D * 65];
    __shared__ float Usm[D * 65];
    for (int i = threadIdx.x; i < D * D; i += blockDim.x) {
        Wsm[(i >> 6) * 65 + (i & 63)] = W[i];
        Usm[(i >> 6) * 65 + (i & 63)] = Uw[i];
    }
    __syncthreads();

    const int lane = threadIdx.x & 63;
    const int wid  = threadIdx.x >> 6;
    const float ub = Ub[lane];
    const float* wr = &Wsm[lane * 65];
    const float* ur = &Usm[lane * 65];

    for (int n = blockIdx.x * 4 + wid; n < N; n += gridDim.x * 4) {
        float nfv = nf[n];
        float deg = (nfv > 0.f) ? (1.f / nfv) : 0.f;
        float zv = z[n * D + lane];
        float xv = x[n * D + lane];
        float accw = 0.f, accu = 0.f;
#pragma unroll
        for (int k = 0; k < D; ++k) {
            float zk = __shfl(zv, k);
            float xk = __shfl(xv, k);
            accw = fmaf(zk, wr[k], accw);
            accu = fmaf(xk, ur[k], accu);
        }
        wzux[n * D + lane] = nfv * (accw + deg * (accu + ub));
    }
}

// ---------------- Bucket scatter -------------------------------------------
// Record: other(17b) << 7 | local(6b) << 1 | role(1b). Writes to a bucket are
// cursor-sequential -> dense lines, no RMW blowup.
__global__ __launch_bounds__(256) void bucket_scatter_kernel(
    const int* __restrict__ row, const int* __restrict__ col,
    int* __restrict__ cursor, int* __restrict__ data, int E)
{
    int i = blockIdx.x * blockDim.x + threadIdx.x;
    if (i >= E) return;
    int r = row[i], c = col[i];

    int br = r >> GSH;
    int sr = atomicAdd(&cursor[br], 1);
    if (sr < CAP) data[br * CAP + sr] = (c << 7) | ((r & (GB - 1)) << 1);

    int bc = c >> GSH;
    int sc = atomicAdd(&cursor[bc], 1);
    if (sc < CAP) data[bc * CAP + sc] = (r << 7) | ((c & (GB - 1)) << 1) | 1;
}

// ---------------- Bucketed aggregation -------------------------------------
// One block per bucket of 64 nodes. Self rows + f32 accumulator live in LDS;
// contributions via ds atomics; each output row written once, coalesced.
__global__ __launch_bounds__(256) void bucket_agg_kernel(
    const float4* __restrict__ wzux4,
    const int* __restrict__ cursor, const int* __restrict__ data,
    const float* __restrict__ nf,
    const float4* __restrict__ gamma4, const float4* __restrict__ beta4,
    float4* __restrict__ out4, int N)
{
    __shared__ float4 rows[GB * 17];    // self rows, padded stride 17
    __shared__ float  acc[GB * 68];     // accumulator, padded stride 68

    const int b    = blockIdx.x;
    const int base = b << GSH;
    const int cnt  = min(GB, N - base);
    const int t    = threadIdx.x;
    const int gid  = t >> 4;            // 16 groups of 16 lanes
    const int l    = t & 15;            // float4 slot within row

    // zero accumulator
    for (int i = t; i < GB * 68; i += 256) acc[i] = 0.f;
    // stage self rows
    for (int i = t; i < cnt * 16; i += 256) {
        rows[(i >> 4) * 17 + (i & 15)] = wzux4[(base + (i >> 4)) * 16 + (i & 15)];
    }
    __syncthreads();

    const int count = min(cursor[b], CAP);
    const float4 gm = gamma4[l];
    const float4 bt = beta4[l];
    const int* bdata = &data[b * CAP];

#define PROC(ENT)                                                            \
    {                                                                        \
        int ent = (ENT);                                                     \
        int other = ent >> 7;                                                \
        int local = (ent >> 1) & (GB - 1);                                   \
        float sgn = (ent & 1) ? -1.f : 1.f;                                  \
        float4 o = wzux4[other * 16 + l];                                    \
        float4 s = rows[local * 17 + l];                                     \
        float r0 = fmaxf(sgn * (s.x - o.x), 0.f);                            \
        float r1 = fmaxf(sgn * (s.y - o.y), 0.f);                            \
        float r2 = fmaxf(sgn * (s.z - o.z), 0.f);                            \
        float r3 = fmaxf(sgn * (s.w - o.w), 0.f);                            \
        float ss = r0 + r1 + r2 + r3;                                        \
        float sq = r0 * r0 + r1 * r1 + r2 * r2 + r3 * r3;                    \
        _Pragma("unroll")                                                    \
        for (int off = 1; off < 16; off <<= 1) {                             \
            ss += __shfl_xor(ss, off);                                       \
            sq += __shfl_xor(sq, off);                                       \
        }                                                                    \
        float mu   = ss * (1.f / 64.f);                                      \
        float var  = sq * (1.f / 64.f) - mu * mu;                            \
        float rstd = rsqrtf(var + LN_EPS);                                   \
        float* ap = &acc[local * 68 + l * 4];                                \
        atomicAdd(ap + 0, sgn * ((r0 - mu) * rstd * gm.x + bt.x));           \
        atomicAdd(ap + 1, sgn * ((r1 - mu) * rstd * gm.y + bt.y));           \
        atomicAdd(ap + 2, sgn * ((r2 - mu) * rstd * gm.z + bt.z));           \
        atomicAdd(ap + 3, sgn * ((r3 - mu) * rstd * gm.w + bt.w));           \
    }

    int i = gid;
    for (; i + 16 < count; i += 32) {
        int ea = bdata[i];
        int eb = bdata[i + 16];
        PROC(ea);
        PROC(eb);
    }
    if (i < count) PROC(bdata[i]);
#undef PROC

    __syncthreads();

    // writeout: out[n] = nf[n] * acc_row, coalesced float4
    for (int local = gid; local < cnt; local += 16) {
        int n = base + local;
        float nfv = nf[n];
        const float* ap = &acc[local * 68 + l * 4];
        out4[n * 16 + l] = make_float4(ap[0] * nfv, ap[1] * nfv,
                                       ap[2] * nfv, ap[3] * nfv);
    }
}

// ---------------- Stage 3: out = ALPHA*(-(newz@W)) + (1-ALPHA)*z ----------
__global__ __launch_bounds__(256) void out_kernel(
    const float* __restrict__ accv, const float* __restrict__ z,
    const float* __restrict__ W, float* __restrict__ out, int N)
{
    __shared__ float Wsm[D * 65];
    for (int i = threadIdx.x; i < D * D; i += blockDim.x) {
        Wsm[(i >> 6) * 65 + (i & 63)] = W[i];
    }
    __syncthreads();

    const int lane = threadIdx.x & 63;
    const int wid  = threadIdx.x >> 6;

    for (int n = blockIdx.x * 4 + wid; n < N; n += gridDim.x * 4) {
        float nv = accv[n * D + lane];
        float acc = 0.f;
#pragma unroll
        for (int k = 0; k < D; ++k) {
            float nk = __shfl(nv, k);
            acc = fmaf(nk, Wsm[k * 65 + lane], acc);
        }
        out[n * D + lane] = (1.0f - ALPHA) * z[n * D + lane] - ALPHA * acc;
    }
}

extern "C" void kernel_launch(void* const* d_in, const int* in_sizes, int n_in,
                              void* d_out, int out_size, void* d_ws, size_t ws_size,
                              hipStream_t stream) {
    const float* z     = (const float*)d_in[0];
    const float* x     = (const float*)d_in[1];
    const int*   ei    = (const int*)d_in[2];
    const float* nf    = (const float*)d_in[3];
    const float* W     = (const float*)d_in[4];
    const float* Uw    = (const float*)d_in[5];
    const float* Ub    = (const float*)d_in[6];
    const float* gamma = (const float*)d_in[7];
    const float* beta  = (const float*)d_in[8];

    const int N = in_sizes[0] / D;      // 100000
    const int E = in_sizes[2] / 2;      // 1200000
    const int NBK = (N + GB - 1) >> GSH;

    float* out = (float*)d_out;

    // ---- workspace layout ----
    char* ws = (char*)d_ws;
    size_t off = 0;
    auto alloc = [&](size_t bytes) {
        char* p = ws + off;
        off += (bytes + 255) & ~(size_t)255;
        return p;
    };
    float* wzux   = (float*)alloc((size_t)N * D * sizeof(float));     // 25.6 MB
    int*   cursor = (int*)  alloc((size_t)NBK * sizeof(int));         // 6.3 KB
    int*   bdata  = (int*)  alloc((size_t)NBK * CAP * sizeof(int));   // 12.8 MB

    hipMemsetAsync(cursor, 0, (size_t)NBK * sizeof(int), stream);

    wzux_kernel<<<1024, 256, 0, stream>>>(z, x, nf, W, Uw, Ub, wzux, N);

    int eb = (E + 255) / 256;
    bucket_scatter_kernel<<<eb, 256, 0, stream>>>(ei, ei + E, cursor, bdata, E);

    bucket_agg_kernel<<<NBK, 256, 0, stream>>>(
        (const float4*)wzux, cursor, bdata, nf,
        (const float4*)gamma, (const float4*)beta,
        (float4*)out, N);

    out_kernel<<<1024, 256, 0, stream>>>(out, z, W, out, N);
}

// Round 4
// 700.171 us; speedup vs baseline: 2.1990x; 2.1990x over previous
//
#include <hip/hip_runtime.h>

#define D 64
#define LN_EPS 1e-5f
#define ALPHA 0.5f

#define GB 64            // nodes per bucket
#define GSH 6            // log2(GB)
#define CAP 2048         // bucket capacity (mean ~1535, sigma ~39 -> 13 sigma slack)

// ---------------- Stage 1: WzUx = nf * (z@W.T + deg*(x@U.T + Ub)) ----------
__global__ __launch_bounds__(256) void wzux_kernel(
    const float* __restrict__ z, const float* __restrict__ x,
    const float* __restrict__ nf, const float* __restrict__ W,
    const float* __restrict__ Uw, const float* __restrict__ Ub,
    float* __restrict__ wzux, int N)
{
    __shared__ float Wsm[D * 65];
    __shared__ float Usm[D * 65];
    for (int i = threadIdx.x; i < D * D; i += blockDim.x) {
        Wsm[(i >> 6) * 65 + (i & 63)] = W[i];
        Usm[(i >> 6) * 65 + (i & 63)] = Uw[i];
    }
    __syncthreads();

    const int lane = threadIdx.x & 63;
    const int wid  = threadIdx.x >> 6;
    const float ub = Ub[lane];
    const float* wr = &Wsm[lane * 65];
    const float* ur = &Usm[lane * 65];

    for (int n = blockIdx.x * 4 + wid; n < N; n += gridDim.x * 4) {
        float nfv = nf[n];
        float deg = (nfv > 0.f) ? (1.f / nfv) : 0.f;
        float zv = z[n * D + lane];
        float xv = x[n * D + lane];
        float accw = 0.f, accu = 0.f;
#pragma unroll
        for (int k = 0; k < D; ++k) {
            float zk = __shfl(zv, k);
            float xk = __shfl(xv, k);
            accw = fmaf(zk, wr[k], accw);
            accu = fmaf(xk, ur[k], accu);
        }
        wzux[n * D + lane] = nfv * (accw + deg * (accu + ub));
    }
}

// ---------------- Bucket scatter -------------------------------------------
// Record: other(17b) << 7 | local(6b) << 1 | role(1b). Writes to a bucket are
// cursor-sequential -> dense lines, no RMW blowup.
__global__ __launch_bounds__(256) void bucket_scatter_kernel(
    const int* __restrict__ row, const int* __restrict__ col,
    int* __restrict__ cursor, int* __restrict__ data, int E)
{
    int i = blockIdx.x * blockDim.x + threadIdx.x;
    if (i >= E) return;
    int r = row[i], c = col[i];

    int br = r >> GSH;
    int sr = atomicAdd(&cursor[br], 1);
    if (sr < CAP) data[br * CAP + sr] = (c << 7) | ((r & (GB - 1)) << 1);

    int bc = c >> GSH;
    int sc = atomicAdd(&cursor[bc], 1);
    if (sc < CAP) data[bc * CAP + sc] = (r << 7) | ((c & (GB - 1)) << 1) | 1;
}

// ---------------- Bucketed sort + register aggregation ---------------------
// One block per bucket of 64 nodes. Counting-sort the bucket's entries by
// local node into LDS, then one wave per node accumulates in REGISTERS
// (4 edges in parallel via 16-lane groups) and writes the row once.
__global__ __launch_bounds__(256) void bucket_sort_agg_kernel(
    const float4* __restrict__ wzux4,
    const int* __restrict__ cursor, const int* __restrict__ data,
    const float* __restrict__ nf,
    const float4* __restrict__ gamma4, const float4* __restrict__ beta4,
    float4* __restrict__ out4, int N)
{
    __shared__ int sorted[CAP];
    __shared__ int offs[GB + 1];   // after scan: offs[i] = start of local i
    __shared__ int curs[GB];

    const int b    = blockIdx.x;
    const int base = b << GSH;
    const int cntN = min(GB, N - base);
    const int t    = threadIdx.x;

    const int count = min(cursor[b], CAP);
    const int* bdata = &data[b * CAP];

    if (t < GB + 1) offs[t] = 0;
    __syncthreads();

    // count per-local degrees (int LDS atomics, ~2048 total)
    for (int i = t; i < count; i += 256) {
        int local = (bdata[i] >> 1) & (GB - 1);
        atomicAdd(&offs[local + 1], 1);
    }
    __syncthreads();

    // inclusive scan of offs[1..64] by wave 0 (64 lanes)
    if (t < GB) {
        int v = offs[t + 1];
#pragma unroll
        for (int off = 1; off < GB; off <<= 1) {
            int u = __shfl_up(v, off);
            if (t >= off) v += u;
        }
        offs[t + 1] = v;
    }
    __syncthreads();
    if (t < GB) curs[t] = offs[t];
    __syncthreads();

    // scatter into sorted order
    for (int i = t; i < count; i += 256) {
        int ent = bdata[i];
        int local = (ent >> 1) & (GB - 1);
        sorted[atomicAdd(&curs[local], 1)] = ent;
    }
    __syncthreads();

    // register aggregation: wave wid handles locals wid, wid+4, ...
    const int lane = t & 63;
    const int wid  = t >> 6;
    const int g = lane >> 4;      // edge slot within wave
    const int l = lane & 15;      // float4 slot within row
    const float4 gm = gamma4[l];
    const float4 bt = beta4[l];

    for (int local = wid; local < cntN; local += 4) {
        const int s = offs[local];
        const int e = offs[local + 1];
        const int n = base + local;
        const float4 self = wzux4[n * 16 + l];
        float4 acc = make_float4(0.f, 0.f, 0.f, 0.f);

#define PROC(IDX)                                                            \
        {                                                                    \
            int i_ = (IDX);                                                  \
            bool act = (i_ < e);                                             \
            int ent = act ? sorted[i_] : 0;                                  \
            int other = ent >> 7;                                            \
            float sgn = (ent & 1) ? -1.f : 1.f;                              \
            float4 o = act ? wzux4[other * 16 + l] : self;                   \
            float r0 = fmaxf(sgn * (self.x - o.x), 0.f);                     \
            float r1 = fmaxf(sgn * (self.y - o.y), 0.f);                     \
            float r2 = fmaxf(sgn * (self.z - o.z), 0.f);                     \
            float r3 = fmaxf(sgn * (self.w - o.w), 0.f);                     \
            float ss = r0 + r1 + r2 + r3;                                    \
            float sq = r0 * r0 + r1 * r1 + r2 * r2 + r3 * r3;                \
            _Pragma("unroll")                                                \
            for (int off = 1; off < 16; off <<= 1) {                         \
                ss += __shfl_xor(ss, off);                                   \
                sq += __shfl_xor(sq, off);                                   \
            }                                                                \
            float mu   = ss * (1.f / 64.f);                                  \
            float var  = sq * (1.f / 64.f) - mu * mu;                        \
            float rstd = rsqrtf(var + LN_EPS);                               \
            if (act) {                                                       \
                acc.x += sgn * ((r0 - mu) * rstd * gm.x + bt.x);             \
                acc.y += sgn * ((r1 - mu) * rstd * gm.y + bt.y);             \
                acc.z += sgn * ((r2 - mu) * rstd * gm.z + bt.z);             \
                acc.w += sgn * ((r3 - mu) * rstd * gm.w + bt.w);             \
            }                                                                \
        }

        int i = s + g;
        for (; i + 4 < e; i += 8) {
            PROC(i);
            PROC(i + 4);
        }
        PROC(i);
#undef PROC

        // reduce across the 4 edge slots
#pragma unroll
        for (int m = 16; m < 64; m <<= 1) {
            acc.x += __shfl_xor(acc.x, m);
            acc.y += __shfl_xor(acc.y, m);
            acc.z += __shfl_xor(acc.z, m);
            acc.w += __shfl_xor(acc.w, m);
        }

        if (g == 0) {
            float nfv = nf[n];
            out4[n * 16 + l] = make_float4(acc.x * nfv, acc.y * nfv,
                                           acc.z * nfv, acc.w * nfv);
        }
    }
}

// ---------------- Stage 3: out = ALPHA*(-(newz@W)) + (1-ALPHA)*z ----------
__global__ __launch_bounds__(256) void out_kernel(
    const float* __restrict__ accv, const float* __restrict__ z,
    const float* __restrict__ W, float* __restrict__ out, int N)
{
    __shared__ float Wsm[D * 65];
    for (int i = threadIdx.x; i < D * D; i += blockDim.x) {
        Wsm[(i >> 6) * 65 + (i & 63)] = W[i];
    }
    __syncthreads();

    const int lane = threadIdx.x & 63;
    const int wid  = threadIdx.x >> 6;

    for (int n = blockIdx.x * 4 + wid; n < N; n += gridDim.x * 4) {
        float nv = accv[n * D + lane];
        float acc = 0.f;
#pragma unroll
        for (int k = 0; k < D; ++k) {
            float nk = __shfl(nv, k);
            acc = fmaf(nk, Wsm[k * 65 + lane], acc);
        }
        out[n * D + lane] = (1.0f - ALPHA) * z[n * D + lane] - ALPHA * acc;
    }
}

extern "C" void kernel_launch(void* const* d_in, const int* in_sizes, int n_in,
                              void* d_out, int out_size, void* d_ws, size_t ws_size,
                              hipStream_t stream) {
    const float* z     = (const float*)d_in[0];
    const float* x     = (const float*)d_in[1];
    const int*   ei    = (const int*)d_in[2];
    const float* nf    = (const float*)d_in[3];
    const float* W     = (const float*)d_in[4];
    const float* Uw    = (const float*)d_in[5];
    const float* Ub    = (const float*)d_in[6];
    const float* gamma = (const float*)d_in[7];
    const float* beta  = (const float*)d_in[8];

    const int N = in_sizes[0] / D;      // 100000
    const int E = in_sizes[2] / 2;      // 1200000
    const int NBK = (N + GB - 1) >> GSH;

    float* out = (float*)d_out;

    // ---- workspace layout ----
    char* ws = (char*)d_ws;
    size_t off = 0;
    auto alloc = [&](size_t bytes) {
        char* p = ws + off;
        off += (bytes + 255) & ~(size_t)255;
        return p;
    };
    float* wzux   = (float*)alloc((size_t)N * D * sizeof(float));     // 25.6 MB
    int*   cursor = (int*)  alloc((size_t)NBK * sizeof(int));         // 6.3 KB
    int*   bdata  = (int*)  alloc((size_t)NBK * CAP * sizeof(int));   // 12.8 MB

    hipMemsetAsync(cursor, 0, (size_t)NBK * sizeof(int), stream);

    wzux_kernel<<<1024, 256, 0, stream>>>(z, x, nf, W, Uw, Ub, wzux, N);

    int eb = (E + 255) / 256;
    bucket_scatter_kernel<<<eb, 256, 0, stream>>>(ei, ei + E, cursor, bdata, E);

    bucket_sort_agg_kernel<<<NBK, 256, 0, stream>>>(
        (const float4*)wzux, cursor, bdata, nf,
        (const float4*)gamma, (const float4*)beta,
        (float4*)out, N);

    out_kernel<<<1024, 256, 0, stream>>>(out, z, W, out, N);
}

// Round 5
// 458.765 us; speedup vs baseline: 3.3562x; 1.5262x over previous
//
#include <hip/hip_runtime.h>

#define D 64
#define LN_EPS 1e-5f
#define ALPHA 0.5f

#define GB 64            // nodes per bucket
#define GSH 6            // log2(GB)
#define NSUB 8           // sub-buckets per bucket (one per XCD)
#define CAPS 320         // per-sub capacity (mean ~192, sigma ~15 -> +8.5 sigma)
#define CAP 2048         // sorted-bucket capacity (mean ~1535, sigma ~39)

// wave-uniform XCD id (0..7), measured-reliable on gfx950 (HW_REG_XCC_ID)
__device__ __forceinline__ unsigned xcc_id() {
    unsigned v;
    asm volatile("s_getreg_b32 %0, hwreg(HW_REG_XCC_ID)" : "=s"(v));
    return v & (NSUB - 1);
}

// ---------------- Stage 1: WzUx = nf * (z@W.T + deg*(x@U.T + Ub)) ----------
__global__ __launch_bounds__(256) void wzux_kernel(
    const float* __restrict__ z, const float* __restrict__ x,
    const float* __restrict__ nf, const float* __restrict__ W,
    const float* __restrict__ Uw, const float* __restrict__ Ub,
    float* __restrict__ wzux, int N)
{
    __shared__ float Wsm[D * 65];
    __shared__ float Usm[D * 65];
    for (int i = threadIdx.x; i < D * D; i += blockDim.x) {
        Wsm[(i >> 6) * 65 + (i & 63)] = W[i];
        Usm[(i >> 6) * 65 + (i & 63)] = Uw[i];
    }
    __syncthreads();

    const int lane = threadIdx.x & 63;
    const int wid  = threadIdx.x >> 6;
    const float ub = Ub[lane];
    const float* wr = &Wsm[lane * 65];
    const float* ur = &Usm[lane * 65];

    for (int n = blockIdx.x * 4 + wid; n < N; n += gridDim.x * 4) {
        float nfv = nf[n];
        float deg = (nfv > 0.f) ? (1.f / nfv) : 0.f;
        float zv = z[n * D + lane];
        float xv = x[n * D + lane];
        float accw = 0.f, accu = 0.f;
#pragma unroll
        for (int k = 0; k < D; ++k) {
            float zk = __shfl(zv, k);
            float xk = __shfl(xv, k);
            accw = fmaf(zk, wr[k], accw);
            accu = fmaf(xk, ur[k], accu);
        }
        wzux[n * D + lane] = nfv * (accw + deg * (accu + ub));
    }
}

// ---------------- Bucket scatter (XCD-local sub-cursors) -------------------
// Record: other(17b) << 7 | local(6b) << 1 | role(1b).
// sub = XCD id: each (bucket,sub) region's cursor AND data lines are touched
// by exactly one XCD's L2 -> local atomics, dense full-line writebacks.
__global__ __launch_bounds__(256) void bucket_scatter_kernel(
    const int* __restrict__ row, const int* __restrict__ col,
    int* __restrict__ cursor, int* __restrict__ data, int E)
{
    int i = blockIdx.x * blockDim.x + threadIdx.x;
    if (i >= E) return;
    const int sub = xcc_id();
    int r = row[i], c = col[i];

    int br = r >> GSH;
    int sr = atomicAdd(&cursor[br * NSUB + sub], 1);
    if (sr < CAPS)
        data[(br * NSUB + sub) * CAPS + sr] = (c << 7) | ((r & (GB - 1)) << 1);

    int bc = c >> GSH;
    int sc = atomicAdd(&cursor[bc * NSUB + sub], 1);
    if (sc < CAPS)
        data[(bc * NSUB + sub) * CAPS + sc] = (r << 7) | ((c & (GB - 1)) << 1) | 1;
}

// ---------------- Bucketed sort + register aggregation ---------------------
// One block per bucket of 64 nodes. Counting-sort the bucket's entries
// (from 8 sub-regions) into LDS, then one wave per node accumulates in
// REGISTERS (4 edges in parallel via 16-lane groups); row stored once.
__global__ __launch_bounds__(256) void bucket_sort_agg_kernel(
    const float4* __restrict__ wzux4,
    const int* __restrict__ cursor, const int* __restrict__ data,
    const float* __restrict__ nf,
    const float4* __restrict__ gamma4, const float4* __restrict__ beta4,
    float4* __restrict__ out4, int N)
{
    __shared__ int sorted[CAP];
    __shared__ int offs[GB + 1];   // after scan: offs[i] = start of local i
    __shared__ int curs[GB];

    const int b    = blockIdx.x;
    const int base = b << GSH;
    const int cntN = min(GB, N - base);
    const int t    = threadIdx.x;

    const int* bcur  = &cursor[b * NSUB];
    const int* bdata = &data[(size_t)b * NSUB * CAPS];

    if (t < GB + 1) offs[t] = 0;
    __syncthreads();

    // count per-local degrees across the 8 sub-regions
    for (int sub = 0; sub < NSUB; ++sub) {
        const int cs = min(bcur[sub], CAPS);
        for (int i = t; i < cs; i += 256) {
            int local = (bdata[sub * CAPS + i] >> 1) & (GB - 1);
            atomicAdd(&offs[local + 1], 1);
        }
    }
    __syncthreads();

    // inclusive scan of offs[1..64] by wave 0
    if (t < GB) {
        int v = offs[t + 1];
#pragma unroll
        for (int off = 1; off < GB; off <<= 1) {
            int u = __shfl_up(v, off);
            if (t >= off) v += u;
        }
        offs[t + 1] = v;
    }
    __syncthreads();
    if (t < GB) curs[t] = offs[t];
    __syncthreads();

    // scatter into sorted order
    for (int sub = 0; sub < NSUB; ++sub) {
        const int cs = min(bcur[sub], CAPS);
        for (int i = t; i < cs; i += 256) {
            int ent = bdata[sub * CAPS + i];
            int local = (ent >> 1) & (GB - 1);
            int p = atomicAdd(&curs[local], 1);
            if (p < CAP) sorted[p] = ent;
        }
    }
    __syncthreads();

    // register aggregation: wave wid handles locals wid, wid+4, ...
    const int lane = t & 63;
    const int wid  = t >> 6;
    const int g = lane >> 4;      // edge slot within wave
    const int l = lane & 15;      // float4 slot within row
    const float4 gm = gamma4[l];
    const float4 bt = beta4[l];

    for (int local = wid; local < cntN; local += 4) {
        const int s = offs[local];
        const int e = min(offs[local + 1], CAP);
        const int n = base + local;
        const float4 self = wzux4[n * 16 + l];
        float4 acc = make_float4(0.f, 0.f, 0.f, 0.f);

#define PROC2(ENT, OROW)                                                     \
        {                                                                    \
            int ent = (ENT);                                                 \
            float sgn = (ent & 1) ? -1.f : 1.f;                              \
            float4 o = (OROW);                                               \
            float r0 = fmaxf(sgn * (self.x - o.x), 0.f);                     \
            float r1 = fmaxf(sgn * (self.y - o.y), 0.f);                     \
            float r2 = fmaxf(sgn * (self.z - o.z), 0.f);                     \
            float r3 = fmaxf(sgn * (self.w - o.w), 0.f);                     \
            float ss = r0 + r1 + r2 + r3;                                    \
            float sq = r0 * r0 + r1 * r1 + r2 * r2 + r3 * r3;                \
            _Pragma("unroll")                                                \
            for (int off = 1; off < 16; off <<= 1) {                         \
                ss += __shfl_xor(ss, off);                                   \
                sq += __shfl_xor(sq, off);                                   \
            }                                                                \
            float mu   = ss * (1.f / 64.f);                                  \
            float var  = sq * (1.f / 64.f) - mu * mu;                        \
            float rstd = rsqrtf(var + LN_EPS);                               \
            acc.x += sgn * ((r0 - mu) * rstd * gm.x + bt.x);                 \
            acc.y += sgn * ((r1 - mu) * rstd * gm.y + bt.y);                 \
            acc.z += sgn * ((r2 - mu) * rstd * gm.z + bt.z);                 \
            acc.w += sgn * ((r3 - mu) * rstd * gm.w + bt.w);                 \
        }

        int i = s + g;
        for (; i + 4 < e; i += 8) {
            // issue both gathers before either LN computation (latency overlap)
            int ea = sorted[i];
            int eb = sorted[i + 4];
            float4 oa = wzux4[(ea >> 7) * 16 + l];
            float4 ob = wzux4[(eb >> 7) * 16 + l];
            PROC2(ea, oa);
            PROC2(eb, ob);
        }
        if (i < e) {
            int ea = sorted[i];
            float4 oa = wzux4[(ea >> 7) * 16 + l];
            PROC2(ea, oa);
        }
#undef PROC2

        // reduce across the 4 edge slots
#pragma unroll
        for (int m = 16; m < 64; m <<= 1) {
            acc.x += __shfl_xor(acc.x, m);
            acc.y += __shfl_xor(acc.y, m);
            acc.z += __shfl_xor(acc.z, m);
            acc.w += __shfl_xor(acc.w, m);
        }

        if (g == 0) {
            float nfv = nf[n];
            out4[n * 16 + l] = make_float4(acc.x * nfv, acc.y * nfv,
                                           acc.z * nfv, acc.w * nfv);
        }
    }
}

// ---------------- Stage 3: out = ALPHA*(-(newz@W)) + (1-ALPHA)*z ----------
__global__ __launch_bounds__(256) void out_kernel(
    const float* __restrict__ accv, const float* __restrict__ z,
    const float* __restrict__ W, float* __restrict__ out, int N)
{
    __shared__ float Wsm[D * 65];
    for (int i = threadIdx.x; i < D * D; i += blockDim.x) {
        Wsm[(i >> 6) * 65 + (i & 63)] = W[i];
    }
    __syncthreads();

    const int lane = threadIdx.x & 63;
    const int wid  = threadIdx.x >> 6;

    for (int n = blockIdx.x * 4 + wid; n < N; n += gridDim.x * 4) {
        float nv = accv[n * D + lane];
        float acc = 0.f;
#pragma unroll
        for (int k = 0; k < D; ++k) {
            float nk = __shfl(nv, k);
            acc = fmaf(nk, Wsm[k * 65 + lane], acc);
        }
        out[n * D + lane] = (1.0f - ALPHA) * z[n * D + lane] - ALPHA * acc;
    }
}

extern "C" void kernel_launch(void* const* d_in, const int* in_sizes, int n_in,
                              void* d_out, int out_size, void* d_ws, size_t ws_size,
                              hipStream_t stream) {
    const float* z     = (const float*)d_in[0];
    const float* x     = (const float*)d_in[1];
    const int*   ei    = (const int*)d_in[2];
    const float* nf    = (const float*)d_in[3];
    const float* W     = (const float*)d_in[4];
    const float* Uw    = (const float*)d_in[5];
    const float* Ub    = (const float*)d_in[6];
    const float* gamma = (const float*)d_in[7];
    const float* beta  = (const float*)d_in[8];

    const int N = in_sizes[0] / D;      // 100000
    const int E = in_sizes[2] / 2;      // 1200000
    const int NBK = (N + GB - 1) >> GSH;

    float* out = (float*)d_out;

    // ---- workspace layout ----
    char* ws = (char*)d_ws;
    size_t off = 0;
    auto alloc = [&](size_t bytes) {
        char* p = ws + off;
        off += (bytes + 255) & ~(size_t)255;
        return p;
    };
    float* wzux   = (float*)alloc((size_t)N * D * sizeof(float));            // 25.6 MB
    int*   cursor = (int*)  alloc((size_t)NBK * NSUB * sizeof(int));         // 50 KB
    int*   bdata  = (int*)  alloc((size_t)NBK * NSUB * CAPS * sizeof(int));  // 16 MB

    hipMemsetAsync(cursor, 0, (size_t)NBK * NSUB * sizeof(int), stream);

    wzux_kernel<<<1024, 256, 0, stream>>>(z, x, nf, W, Uw, Ub, wzux, N);

    int eb = (E + 255) / 256;
    bucket_scatter_kernel<<<eb, 256, 0, stream>>>(ei, ei + E, cursor, bdata, E);

    bucket_sort_agg_kernel<<<NBK, 256, 0, stream>>>(
        (const float4*)wzux, cursor, bdata, nf,
        (const float4*)gamma, (const float4*)beta,
        (float4*)out, N);

    out_kernel<<<1024, 256, 0, stream>>>(out, z, W, out, N);
}

// Round 6
// 383.494 us; speedup vs baseline: 4.0149x; 1.1963x over previous
//
#include <hip/hip_runtime.h>

#define D 64
#define LN_EPS 1e-5f
#define ALPHA 0.5f

#define GB 64            // nodes per bucket
#define GSH 6            // log2(GB)
#define NSUB 8           // sub-buckets per bucket (one per XCD)
#define CAPS 320         // per-sub capacity (mean ~192, sigma ~15 -> +8.5 sigma)
#define CAP 2048         // sorted-bucket capacity (mean ~1535, sigma ~39)

// wave-uniform XCD id (0..7), measured-reliable on gfx950 (HW_REG_XCC_ID)
__device__ __forceinline__ unsigned xcc_id() {
    unsigned v;
    asm volatile("s_getreg_b32 %0, hwreg(HW_REG_XCC_ID)" : "=s"(v));
    return v & (NSUB - 1);
}

// ---------------- Stage 1: WzUx = nf * (z@W.T + deg*(x@U.T + Ub)) ----------
// Lane d holds W row d and U row d in VGPRs (loop-invariant). Node rows z/x
// are read via wave-uniform float4 loads (readfirstlane-certified) -> no LDS
// ops, no shuffles; inner loop is pure v_fmac.
__global__ __launch_bounds__(256) void wzux_kernel(
    const float* __restrict__ z, const float* __restrict__ x,
    const float* __restrict__ nf, const float* __restrict__ W,
    const float* __restrict__ Uw, const float* __restrict__ Ub,
    float* __restrict__ wzux, int N)
{
    const int lane = threadIdx.x & 63;
    const int wid  = threadIdx.x >> 6;

    float4 wreg[16], ureg[16];
    {
        const float4* wr = (const float4*)(W  + (size_t)lane * D);
        const float4* ur = (const float4*)(Uw + (size_t)lane * D);
#pragma unroll
        for (int i = 0; i < 16; ++i) { wreg[i] = wr[i]; ureg[i] = ur[i]; }
    }
    const float ub = Ub[lane];

    for (int n = blockIdx.x * 4 + wid; n < N; n += gridDim.x * 4) {
        const int un = __builtin_amdgcn_readfirstlane(n);
        const float4* zr = (const float4*)(z + (size_t)un * D);
        const float4* xr = (const float4*)(x + (size_t)un * D);
        float accw = 0.f, accu = 0.f;
#pragma unroll
        for (int c = 0; c < 16; ++c) {
            float4 zc = zr[c];
            float4 xc = xr[c];
            accw = fmaf(zc.x, wreg[c].x, accw);
            accw = fmaf(zc.y, wreg[c].y, accw);
            accw = fmaf(zc.z, wreg[c].z, accw);
            accw = fmaf(zc.w, wreg[c].w, accw);
            accu = fmaf(xc.x, ureg[c].x, accu);
            accu = fmaf(xc.y, ureg[c].y, accu);
            accu = fmaf(xc.z, ureg[c].z, accu);
            accu = fmaf(xc.w, ureg[c].w, accu);
        }
        float nfv = nf[un];
        float deg = (nfv > 0.f) ? (1.f / nfv) : 0.f;
        wzux[(size_t)un * D + lane] = nfv * (accw + deg * (accu + ub));
    }
}

// ---------------- Bucket scatter (XCD-local sub-cursors) -------------------
// Record: other(17b) << 7 | local(6b) << 1 | role(1b).
__global__ __launch_bounds__(256) void bucket_scatter_kernel(
    const int* __restrict__ row, const int* __restrict__ col,
    int* __restrict__ cursor, int* __restrict__ data, int E)
{
    int i = blockIdx.x * blockDim.x + threadIdx.x;
    if (i >= E) return;
    const int sub = xcc_id();
    int r = row[i], c = col[i];

    int br = r >> GSH;
    int sr = atomicAdd(&cursor[br * NSUB + sub], 1);
    if (sr < CAPS)
        data[(br * NSUB + sub) * CAPS + sr] = (c << 7) | ((r & (GB - 1)) << 1);

    int bc = c >> GSH;
    int sc = atomicAdd(&cursor[bc * NSUB + sub], 1);
    if (sc < CAPS)
        data[(bc * NSUB + sub) * CAPS + sc] = (r << 7) | ((c & (GB - 1)) << 1) | 1;
}

// ---------------- Bucketed sort + register aggregation ---------------------
__global__ __launch_bounds__(256) void bucket_sort_agg_kernel(
    const float4* __restrict__ wzux4,
    const int* __restrict__ cursor, const int* __restrict__ data,
    const float* __restrict__ nf,
    const float4* __restrict__ gamma4, const float4* __restrict__ beta4,
    float4* __restrict__ out4, int N)
{
    __shared__ int sorted[CAP];
    __shared__ int offs[GB + 1];   // after scan: offs[i] = start of local i
    __shared__ int curs[GB];

    const int b    = blockIdx.x;
    const int base = b << GSH;
    const int cntN = min(GB, N - base);
    const int t    = threadIdx.x;

    const int* bcur  = &cursor[b * NSUB];
    const int* bdata = &data[(size_t)b * NSUB * CAPS];

    if (t < GB + 1) offs[t] = 0;
    __syncthreads();

    for (int sub = 0; sub < NSUB; ++sub) {
        const int cs = min(bcur[sub], CAPS);
        for (int i = t; i < cs; i += 256) {
            int local = (bdata[sub * CAPS + i] >> 1) & (GB - 1);
            atomicAdd(&offs[local + 1], 1);
        }
    }
    __syncthreads();

    if (t < GB) {
        int v = offs[t + 1];
#pragma unroll
        for (int off = 1; off < GB; off <<= 1) {
            int u = __shfl_up(v, off);
            if (t >= off) v += u;
        }
        offs[t + 1] = v;
    }
    __syncthreads();
    if (t < GB) curs[t] = offs[t];
    __syncthreads();

    for (int sub = 0; sub < NSUB; ++sub) {
        const int cs = min(bcur[sub], CAPS);
        for (int i = t; i < cs; i += 256) {
            int ent = bdata[sub * CAPS + i];
            int local = (ent >> 1) & (GB - 1);
            int p = atomicAdd(&curs[local], 1);
            if (p < CAP) sorted[p] = ent;
        }
    }
    __syncthreads();

    const int lane = t & 63;
    const int wid  = t >> 6;
    const int g = lane >> 4;      // edge slot within wave
    const int l = lane & 15;      // float4 slot within row
    const float4 gm = gamma4[l];
    const float4 bt = beta4[l];

    for (int local = wid; local < cntN; local += 4) {
        const int s = offs[local];
        const int e = min(offs[local + 1], CAP);
        const int n = base + local;
        const float4 self = wzux4[n * 16 + l];
        float4 acc = make_float4(0.f, 0.f, 0.f, 0.f);

#define PROC2(ENT, OROW)                                                     \
        {                                                                    \
            int ent = (ENT);                                                 \
            float sgn = (ent & 1) ? -1.f : 1.f;                              \
            float4 o = (OROW);                                               \
            float r0 = fmaxf(sgn * (self.x - o.x), 0.f);                     \
            float r1 = fmaxf(sgn * (self.y - o.y), 0.f);                     \
            float r2 = fmaxf(sgn * (self.z - o.z), 0.f);                     \
            float r3 = fmaxf(sgn * (self.w - o.w), 0.f);                     \
            float ss = r0 + r1 + r2 + r3;                                    \
            float sq = r0 * r0 + r1 * r1 + r2 * r2 + r3 * r3;                \
            _Pragma("unroll")                                                \
            for (int off = 1; off < 16; off <<= 1) {                         \
                ss += __shfl_xor(ss, off);                                   \
                sq += __shfl_xor(sq, off);                                   \
            }                                                                \
            float mu   = ss * (1.f / 64.f);                                  \
            float var  = sq * (1.f / 64.f) - mu * mu;                        \
            float rstd = rsqrtf(var + LN_EPS);                               \
            acc.x += sgn * ((r0 - mu) * rstd * gm.x + bt.x);                 \
            acc.y += sgn * ((r1 - mu) * rstd * gm.y + bt.y);                 \
            acc.z += sgn * ((r2 - mu) * rstd * gm.z + bt.z);                 \
            acc.w += sgn * ((r3 - mu) * rstd * gm.w + bt.w);                 \
        }

        int i = s + g;
        for (; i + 4 < e; i += 8) {
            int ea = sorted[i];
            int eb = sorted[i + 4];
            float4 oa = wzux4[(ea >> 7) * 16 + l];
            float4 ob = wzux4[(eb >> 7) * 16 + l];
            PROC2(ea, oa);
            PROC2(eb, ob);
        }
        if (i < e) {
            int ea = sorted[i];
            float4 oa = wzux4[(ea >> 7) * 16 + l];
            PROC2(ea, oa);
        }
#undef PROC2

#pragma unroll
        for (int m = 16; m < 64; m <<= 1) {
            acc.x += __shfl_xor(acc.x, m);
            acc.y += __shfl_xor(acc.y, m);
            acc.z += __shfl_xor(acc.z, m);
            acc.w += __shfl_xor(acc.w, m);
        }

        if (g == 0) {
            float nfv = nf[n];
            out4[n * 16 + l] = make_float4(acc.x * nfv, acc.y * nfv,
                                           acc.z * nfv, acc.w * nfv);
        }
    }
}

// ---------------- Stage 3: out = ALPHA*(-(newz@W)) + (1-ALPHA)*z ----------
// Lane d holds W[:,d] in VGPRs; newz row via wave-uniform float4 loads.
// In place on d_out (each row read fully by its owner wave before its store).
__global__ __launch_bounds__(256) void out_kernel(
    const float* accv, const float* __restrict__ z,
    const float* __restrict__ W, float* out, int N)
{
    const int lane = threadIdx.x & 63;
    const int wid  = threadIdx.x >> 6;

    float wcol[D];   // wcol[k] = W[k][lane]
#pragma unroll
    for (int k = 0; k < D; ++k) wcol[k] = W[k * D + lane];

    for (int n = blockIdx.x * 4 + wid; n < N; n += gridDim.x * 4) {
        const int un = __builtin_amdgcn_readfirstlane(n);
        const float4* ar = (const float4*)(accv + (size_t)un * D);
        float acc = 0.f;
#pragma unroll
        for (int c = 0; c < 16; ++c) {
            float4 a = ar[c];
            acc = fmaf(a.x, wcol[c * 4 + 0], acc);
            acc = fmaf(a.y, wcol[c * 4 + 1], acc);
            acc = fmaf(a.z, wcol[c * 4 + 2], acc);
            acc = fmaf(a.w, wcol[c * 4 + 3], acc);
        }
        out[(size_t)un * D + lane] =
            (1.0f - ALPHA) * z[(size_t)un * D + lane] - ALPHA * acc;
    }
}

extern "C" void kernel_launch(void* const* d_in, const int* in_sizes, int n_in,
                              void* d_out, int out_size, void* d_ws, size_t ws_size,
                              hipStream_t stream) {
    const float* z     = (const float*)d_in[0];
    const float* x     = (const float*)d_in[1];
    const int*   ei    = (const int*)d_in[2];
    const float* nf    = (const float*)d_in[3];
    const float* W     = (const float*)d_in[4];
    const float* Uw    = (const float*)d_in[5];
    const float* Ub    = (const float*)d_in[6];
    const float* gamma = (const float*)d_in[7];
    const float* beta  = (const float*)d_in[8];

    const int N = in_sizes[0] / D;      // 100000
    const int E = in_sizes[2] / 2;      // 1200000
    const int NBK = (N + GB - 1) >> GSH;

    float* out = (float*)d_out;

    // ---- workspace layout ----
    char* ws = (char*)d_ws;
    size_t off = 0;
    auto alloc = [&](size_t bytes) {
        char* p = ws + off;
        off += (bytes + 255) & ~(size_t)255;
        return p;
    };
    float* wzux   = (float*)alloc((size_t)N * D * sizeof(float));            // 25.6 MB
    int*   cursor = (int*)  alloc((size_t)NBK * NSUB * sizeof(int));         // 50 KB
    int*   bdata  = (int*)  alloc((size_t)NBK * NSUB * CAPS * sizeof(int));  // 16 MB

    hipMemsetAsync(cursor, 0, (size_t)NBK * NSUB * sizeof(int), stream);

    wzux_kernel<<<1024, 256, 0, stream>>>(z, x, nf, W, Uw, Ub, wzux, N);

    int eb = (E + 255) / 256;
    bucket_scatter_kernel<<<eb, 256, 0, stream>>>(ei, ei + E, cursor, bdata, E);

    bucket_sort_agg_kernel<<<NBK, 256, 0, stream>>>(
        (const float4*)wzux, cursor, bdata, nf,
        (const float4*)gamma, (const float4*)beta,
        (float4*)out, N);

    out_kernel<<<1024, 256, 0, stream>>>(out, z, W, out, N);
}

// Round 7
// 341.408 us; speedup vs baseline: 4.5099x; 1.1233x over previous
//
#include <hip/hip_runtime.h>

#define D 64
#define LN_EPS 1e-5f
#define ALPHA 0.5f

#define GSH 8            // log2(nodes per bucket) = 256-node buckets
#define GBN 256
#define NSUB 8           // per-XCD sub-regions
#define TILE 2048        // edges per radix-scatter block
#define CAPS 1280        // per (bucket,xcd) region capacity (mean ~768)
#define CAPQ 1792        // per quarter-bucket sorted capacity (mean ~1536)
#define OVF_CAP 131072
#define MAXBUCK 400

// wave-uniform XCD id (0..7) on gfx950
__device__ __forceinline__ unsigned xcc_id() {
    unsigned v;
    asm volatile("s_getreg_b32 %0, hwreg(HW_REG_XCC_ID)" : "=s"(v));
    return v & (NSUB - 1);
}

// ---------------- Stage 1: WzUx = nf * (z@W.T + deg*(x@U.T + Ub)) ----------
// Dim-split: block parity selects dims [par*32, par*32+32). Lanes 0-31 hold
// W rows (d) and dot with z; lanes 32-63 hold U rows (same d) and dot with x.
// One shfl_xor(32) combines. 64 weight VGPRs/lane -> stays register-resident.
__global__ __launch_bounds__(256) void wzux_kernel(
    const float* __restrict__ z, const float* __restrict__ x,
    const float* __restrict__ nf, const float* __restrict__ W,
    const float* __restrict__ Uw, const float* __restrict__ Ub,
    float* __restrict__ wzux, int N)
{
    const int lane = threadIdx.x & 63;
    const int wid  = threadIdx.x >> 6;
    const int par  = blockIdx.x & 1;
    const int half = lane >> 5;               // 0: W/z, 1: U/x
    const int d    = par * 32 + (lane & 31);  // output dim

    const float* M = half ? Uw : W;
    float4 wreg[16];
    {
        const float4* wr = (const float4*)(M + (size_t)d * D);
#pragma unroll
        for (int i = 0; i < 16; ++i) wreg[i] = wr[i];
    }
    const float ub = Ub[d];
    const float* base_src = half ? x : z;

    const int start = (blockIdx.x >> 1) * 4 + wid;
    const int step  = (gridDim.x >> 1) * 4;

    for (int n = start; n < N; n += step) {
        const int un = __builtin_amdgcn_readfirstlane(n);
        const float4* src = (const float4*)(base_src + (size_t)un * D);
        float a0 = 0.f, a1 = 0.f, a2 = 0.f, a3 = 0.f;
#pragma unroll
        for (int c = 0; c < 16; ++c) {
            float4 v = src[c];
            a0 = fmaf(v.x, wreg[c].x, a0);
            a1 = fmaf(v.y, wreg[c].y, a1);
            a2 = fmaf(v.z, wreg[c].z, a2);
            a3 = fmaf(v.w, wreg[c].w, a3);
        }
        float acc = (a0 + a1) + (a2 + a3);
        float other = __shfl_xor(acc, 32);    // partner lane shares d
        if (half == 0) {
            float nfv = nf[un];
            float deg = (nfv > 0.f) ? (1.f / nfv) : 0.f;
            wzux[(size_t)un * D + d] = nfv * (acc + deg * (other + ub));
        }
    }
}

// ---------------- Block-aggregated radix scatter ---------------------------
// Record: other(17b) << 9 | local8 << 1 | role. Per 2048-edge tile: LDS count
// per bucket, ONE reserve atomic per nonempty bucket, then ~10-entry dense
// runs into (bucket, xcd) regions. Overflow -> global (bucket, rec) list.
__global__ __launch_bounds__(256) void radix_scatter_kernel(
    const int* __restrict__ row, const int* __restrict__ col,
    int* __restrict__ gcur, int* __restrict__ data,
    int* __restrict__ ovf_cnt, int2* __restrict__ ovf,
    int E, int nbuck)
{
    __shared__ int cnt[MAXBUCK];
    __shared__ int gbase[MAXBUCK];
    const int t  = threadIdx.x;
    const int e0 = blockIdx.x * TILE;
    const int e1 = min(e0 + TILE, E);
    const unsigned sub = xcc_id();

    for (int i = t; i < nbuck; i += 256) cnt[i] = 0;
    __syncthreads();

    for (int e = e0 + t; e < e1; e += 256) {
        atomicAdd(&cnt[row[e] >> GSH], 1);
        atomicAdd(&cnt[col[e] >> GSH], 1);
    }
    __syncthreads();

    for (int b = t; b < nbuck; b += 256) {
        int c = cnt[b];
        gbase[b] = (c > 0) ? atomicAdd(&gcur[b * NSUB + sub], c) : 0;
    }
    __syncthreads();

    for (int e = e0 + t; e < e1; e += 256) {
        int r = row[e], c = col[e];
        {
            int b = r >> GSH;
            int s = atomicSub(&cnt[b], 1) - 1;
            int pos = gbase[b] + s;
            int rec = (c << 9) | ((r & (GBN - 1)) << 1);
            if (pos < CAPS) data[(b * NSUB + (int)sub) * CAPS + pos] = rec;
            else { int o = atomicAdd(ovf_cnt, 1);
                   if (o < OVF_CAP) ovf[o] = make_int2(b, rec); }
        }
        {
            int b = c >> GSH;
            int s = atomicSub(&cnt[b], 1) - 1;
            int pos = gbase[b] + s;
            int rec = (r << 9) | ((c & (GBN - 1)) << 1) | 1;
            if (pos < CAPS) data[(b * NSUB + (int)sub) * CAPS + pos] = rec;
            else { int o = atomicAdd(ovf_cnt, 1);
                   if (o < OVF_CAP) ovf[o] = make_int2(b, rec); }
        }
    }
}

// ---------------- Quarter-bucket sort + register aggregation ---------------
// One block per 64 nodes (quarter of a 256-node bucket). Filter the bucket's
// records on the top-2 local bits, counting-sort into LDS, then one wave per
// node accumulates in registers; each output row written once.
__global__ __launch_bounds__(256) void bucket_sort_agg_kernel(
    const float4* __restrict__ wzux4,
    const int* __restrict__ gcur, const int* __restrict__ data,
    const int* __restrict__ ovf_cnt, const int2* __restrict__ ovf,
    const float* __restrict__ nf,
    const float4* __restrict__ gamma4, const float4* __restrict__ beta4,
    float4* __restrict__ out4, int N)
{
    __shared__ int sorted[CAPQ];
    __shared__ int offs[65];
    __shared__ int curs[64];

    const int blk    = blockIdx.x;       // 64-node group
    const int base   = blk << 6;
    const int cntN   = min(64, N - base);
    const int bucket = blk >> 2;
    const int q      = blk & 3;
    const int t      = threadIdx.x;

    if (t < 65) offs[t] = 0;
    __syncthreads();

    const int ocnt = min(*ovf_cnt, OVF_CAP);

    // count (filtered by quarter)
    for (int sub = 0; sub < NSUB; ++sub) {
        const int cs = min(gcur[bucket * NSUB + sub], CAPS);
        const int* p = &data[(bucket * NSUB + sub) * CAPS];
        for (int i = t; i < cs; i += 256) {
            int l8 = (p[i] >> 1) & (GBN - 1);
            if ((l8 >> 6) == q) atomicAdd(&offs[(l8 & 63) + 1], 1);
        }
    }
    for (int i = t; i < ocnt; i += 256) {
        int2 v = ovf[i];
        int l8 = (v.y >> 1) & (GBN - 1);
        if (v.x == bucket && (l8 >> 6) == q) atomicAdd(&offs[(l8 & 63) + 1], 1);
    }
    __syncthreads();

    // inclusive scan of offs[1..64] by wave 0
    if (t < 64) {
        int v = offs[t + 1];
#pragma unroll
        for (int off = 1; off < 64; off <<= 1) {
            int u = __shfl_up(v, off);
            if (t >= off) v += u;
        }
        offs[t + 1] = v;
    }
    __syncthreads();
    if (t < 64) curs[t] = offs[t];
    __syncthreads();

    // place
    for (int sub = 0; sub < NSUB; ++sub) {
        const int cs = min(gcur[bucket * NSUB + sub], CAPS);
        const int* p = &data[(bucket * NSUB + sub) * CAPS];
        for (int i = t; i < cs; i += 256) {
            int rec = p[i];
            int l8 = (rec >> 1) & (GBN - 1);
            if ((l8 >> 6) == q) {
                int pos = atomicAdd(&curs[l8 & 63], 1);
                if (pos < CAPQ) sorted[pos] = rec;
            }
        }
    }
    for (int i = t; i < ocnt; i += 256) {
        int2 v = ovf[i];
        int l8 = (v.y >> 1) & (GBN - 1);
        if (v.x == bucket && (l8 >> 6) == q) {
            int pos = atomicAdd(&curs[l8 & 63], 1);
            if (pos < CAPQ) sorted[pos] = v.y;
        }
    }
    __syncthreads();

    // register aggregation: wave wid handles locals wid, wid+4, ...
    const int lane = t & 63;
    const int wid  = t >> 6;
    const int g = lane >> 4;      // edge slot within wave
    const int l = lane & 15;      // float4 slot within row
    const float4 gm = gamma4[l];
    const float4 bt = beta4[l];

    for (int local = wid; local < cntN; local += 4) {
        const int s = min(offs[local], CAPQ);
        const int e = min(offs[local + 1], CAPQ);
        const int n = base + local;
        const float4 self = wzux4[n * 16 + l];
        float4 acc = make_float4(0.f, 0.f, 0.f, 0.f);

#define PROC2(ENT, OROW)                                                     \
        {                                                                    \
            int ent = (ENT);                                                 \
            float sgn = (ent & 1) ? -1.f : 1.f;                              \
            float4 o = (OROW);                                               \
            float r0 = fmaxf(sgn * (self.x - o.x), 0.f);                     \
            float r1 = fmaxf(sgn * (self.y - o.y), 0.f);                     \
            float r2 = fmaxf(sgn * (self.z - o.z), 0.f);                     \
            float r3 = fmaxf(sgn * (self.w - o.w), 0.f);                     \
            float ss = r0 + r1 + r2 + r3;                                    \
            float sq = r0 * r0 + r1 * r1 + r2 * r2 + r3 * r3;                \
            _Pragma("unroll")                                                \
            for (int off = 1; off < 16; off <<= 1) {                         \
                ss += __shfl_xor(ss, off);                                   \
                sq += __shfl_xor(sq, off);                                   \
            }                                                                \
            float mu   = ss * (1.f / 64.f);                                  \
            float var  = sq * (1.f / 64.f) - mu * mu;                        \
            float rstd = rsqrtf(var + LN_EPS);                               \
            acc.x += sgn * ((r0 - mu) * rstd * gm.x + bt.x);                 \
            acc.y += sgn * ((r1 - mu) * rstd * gm.y + bt.y);                 \
            acc.z += sgn * ((r2 - mu) * rstd * gm.z + bt.z);                 \
            acc.w += sgn * ((r3 - mu) * rstd * gm.w + bt.w);                 \
        }

        int i = s + g;
        for (; i + 4 < e; i += 8) {
            int ea = sorted[i];
            int eb = sorted[i + 4];
            float4 oa = wzux4[(ea >> 9) * 16 + l];
            float4 ob = wzux4[(eb >> 9) * 16 + l];
            PROC2(ea, oa);
            PROC2(eb, ob);
        }
        if (i < e) {
            int ea = sorted[i];
            float4 oa = wzux4[(ea >> 9) * 16 + l];
            PROC2(ea, oa);
        }
#undef PROC2

#pragma unroll
        for (int m = 16; m < 64; m <<= 1) {
            acc.x += __shfl_xor(acc.x, m);
            acc.y += __shfl_xor(acc.y, m);
            acc.z += __shfl_xor(acc.z, m);
            acc.w += __shfl_xor(acc.w, m);
        }

        if (g == 0) {
            float nfv = nf[n];
            out4[n * 16 + l] = make_float4(acc.x * nfv, acc.y * nfv,
                                           acc.z * nfv, acc.w * nfv);
        }
    }
}

// ---------------- Stage 3: out = ALPHA*(-(newz@W)) + (1-ALPHA)*z ----------
__global__ __launch_bounds__(256) void out_kernel(
    const float* accv, const float* __restrict__ z,
    const float* __restrict__ W, float* out, int N)
{
    const int lane = threadIdx.x & 63;
    const int wid  = threadIdx.x >> 6;

    float wcol[D];   // wcol[k] = W[k][lane]
#pragma unroll
    for (int k = 0; k < D; ++k) wcol[k] = W[k * D + lane];

    for (int n = blockIdx.x * 4 + wid; n < N; n += gridDim.x * 4) {
        const int un = __builtin_amdgcn_readfirstlane(n);
        const float4* ar = (const float4*)(accv + (size_t)un * D);
        float a0 = 0.f, a1 = 0.f, a2 = 0.f, a3 = 0.f;
#pragma unroll
        for (int c = 0; c < 16; ++c) {
            float4 a = ar[c];
            a0 = fmaf(a.x, wcol[c * 4 + 0], a0);
            a1 = fmaf(a.y, wcol[c * 4 + 1], a1);
            a2 = fmaf(a.z, wcol[c * 4 + 2], a2);
            a3 = fmaf(a.w, wcol[c * 4 + 3], a3);
        }
        float acc = (a0 + a1) + (a2 + a3);
        out[(size_t)un * D + lane] =
            (1.0f - ALPHA) * z[(size_t)un * D + lane] - ALPHA * acc;
    }
}

extern "C" void kernel_launch(void* const* d_in, const int* in_sizes, int n_in,
                              void* d_out, int out_size, void* d_ws, size_t ws_size,
                              hipStream_t stream) {
    const float* z     = (const float*)d_in[0];
    const float* x     = (const float*)d_in[1];
    const int*   ei    = (const int*)d_in[2];
    const float* nf    = (const float*)d_in[3];
    const float* W     = (const float*)d_in[4];
    const float* Uw    = (const float*)d_in[5];
    const float* Ub    = (const float*)d_in[6];
    const float* gamma = (const float*)d_in[7];
    const float* beta  = (const float*)d_in[8];

    const int N = in_sizes[0] / D;      // 100000
    const int E = in_sizes[2] / 2;      // 1200000
    const int nbuck = (N + GBN - 1) >> GSH;          // 391

    float* out = (float*)d_out;

    // ---- workspace layout ----
    char* ws = (char*)d_ws;
    size_t off = 0;
    auto alloc = [&](size_t bytes) {
        char* p = ws + off;
        off += (bytes + 255) & ~(size_t)255;
        return p;
    };
    float* wzux    = (float*)alloc((size_t)N * D * sizeof(float));              // 25.6 MB
    int*   gcur    = (int*)  alloc((size_t)nbuck * NSUB * sizeof(int));         // 12.5 KB
    int*   ovf_cnt = (int*)  alloc(sizeof(int));
    int*   data    = (int*)  alloc((size_t)nbuck * NSUB * CAPS * sizeof(int));  // 16 MB
    int2*  ovf     = (int2*) alloc((size_t)OVF_CAP * sizeof(int2));             // 1 MB

    hipMemsetAsync(gcur, 0, (size_t)nbuck * NSUB * sizeof(int), stream);
    hipMemsetAsync(ovf_cnt, 0, sizeof(int), stream);

    wzux_kernel<<<2048, 256, 0, stream>>>(z, x, nf, W, Uw, Ub, wzux, N);

    int sb = (E + TILE - 1) / TILE;
    radix_scatter_kernel<<<sb, 256, 0, stream>>>(ei, ei + E, gcur, data,
                                                 ovf_cnt, ovf, E, nbuck);

    int ab = (N + 63) / 64;
    bucket_sort_agg_kernel<<<ab, 256, 0, stream>>>(
        (const float4*)wzux, gcur, data, ovf_cnt, ovf, nf,
        (const float4*)gamma, (const float4*)beta,
        (float4*)out, N);

    out_kernel<<<2048, 256, 0, stream>>>(out, z, W, out, N);
}

// Round 8
// 322.533 us; speedup vs baseline: 4.7738x; 1.0585x over previous
//
#include <hip/hip_runtime.h>

#define D 64
#define LN_EPS 1e-5f
#define ALPHA 0.5f

#define GSH 8            // log2(nodes per bucket) = 256-node buckets
#define GBN 256
#define NSUB 8           // per-XCD sub-regions
#define TILE 2048        // edges per radix-scatter block
#define CAPS 1280        // per (bucket,xcd) region capacity (mean ~768)
#define CAPQ 1792        // per quarter-bucket sorted capacity (mean ~1536)
#define OVF_CAP 131072
#define MAXBUCK 400
#define WZB 2048         // wzux-role blocks in the fused front kernel

// wave-uniform XCD id (0..7) on gfx950
__device__ __forceinline__ unsigned xcc_id() {
    unsigned v;
    asm volatile("s_getreg_b32 %0, hwreg(HW_REG_XCC_ID)" : "=s"(v));
    return v & (NSUB - 1);
}

// ---------------- Fused front: radix scatter  ||  WzUx transform -----------
// Blocks [0, sb): block-aggregated radix scatter of edge records.
// Blocks [sb, sb+WZB): WzUx = nf * (z@W.T + deg*(x@U.T + Ub)), dim-split.
// No data dependency between the two roles -> co-resident execution hides
// the scatter's atomic latency under wzux's VMEM/VALU work.
__global__ __launch_bounds__(256) void front_kernel(
    const int* __restrict__ row, const int* __restrict__ col,
    int* __restrict__ gcur, int* __restrict__ data,
    int* __restrict__ ovf_cnt, int2* __restrict__ ovf,
    int E, int nbuck, int sb,
    const float* __restrict__ z, const float* __restrict__ x,
    const float* __restrict__ nf, const float* __restrict__ W,
    const float* __restrict__ Uw, const float* __restrict__ Ub,
    float* __restrict__ wzux, int N)
{
    __shared__ int cnt[MAXBUCK];
    __shared__ int gbase[MAXBUCK];
    const int t = threadIdx.x;

    if ((int)blockIdx.x < sb) {
        // ---------------- radix scatter role ----------------
        const int e0 = blockIdx.x * TILE;
        const int e1 = min(e0 + TILE, E);
        const unsigned sub = xcc_id();

        for (int i = t; i < nbuck; i += 256) cnt[i] = 0;
        __syncthreads();

        for (int e = e0 + t; e < e1; e += 256) {
            atomicAdd(&cnt[row[e] >> GSH], 1);
            atomicAdd(&cnt[col[e] >> GSH], 1);
        }
        __syncthreads();

        for (int b = t; b < nbuck; b += 256) {
            int c = cnt[b];
            gbase[b] = (c > 0) ? atomicAdd(&gcur[b * NSUB + sub], c) : 0;
        }
        __syncthreads();

        for (int e = e0 + t; e < e1; e += 256) {
            int r = row[e], c = col[e];
            {
                int b = r >> GSH;
                int s = atomicSub(&cnt[b], 1) - 1;
                int pos = gbase[b] + s;
                int rec = (c << 9) | ((r & (GBN - 1)) << 1);
                if (pos < CAPS) data[(b * NSUB + (int)sub) * CAPS + pos] = rec;
                else { int o = atomicAdd(ovf_cnt, 1);
                       if (o < OVF_CAP) ovf[o] = make_int2(b, rec); }
            }
            {
                int b = c >> GSH;
                int s = atomicSub(&cnt[b], 1) - 1;
                int pos = gbase[b] + s;
                int rec = (r << 9) | ((c & (GBN - 1)) << 1) | 1;
                if (pos < CAPS) data[(b * NSUB + (int)sub) * CAPS + pos] = rec;
                else { int o = atomicAdd(ovf_cnt, 1);
                       if (o < OVF_CAP) ovf[o] = make_int2(b, rec); }
            }
        }
    } else {
        // ---------------- wzux role ----------------
        // Dim-split: block parity selects dims [par*32, par*32+32). Lanes
        // 0-31 hold W rows and dot with z; lanes 32-63 hold U rows and dot
        // with x; one shfl_xor(32) combines. 64 weight VGPRs stay resident.
        const int wb   = blockIdx.x - sb;
        const int lane = t & 63;
        const int wid  = t >> 6;
        const int par  = wb & 1;
        const int half = lane >> 5;               // 0: W/z, 1: U/x
        const int d    = par * 32 + (lane & 31);  // output dim

        const float* M = half ? Uw : W;
        float4 wreg[16];
        {
            const float4* wr = (const float4*)(M + (size_t)d * D);
#pragma unroll
            for (int i = 0; i < 16; ++i) wreg[i] = wr[i];
        }
        const float ub = Ub[d];
        const float* base_src = half ? x : z;

        const int start = (wb >> 1) * 4 + wid;
        const int step  = (WZB >> 1) * 4;

        for (int n = start; n < N; n += step) {
            const int un = __builtin_amdgcn_readfirstlane(n);
            const float4* src = (const float4*)(base_src + (size_t)un * D);
            float a0 = 0.f, a1 = 0.f, a2 = 0.f, a3 = 0.f;
#pragma unroll
            for (int c = 0; c < 16; ++c) {
                float4 v = src[c];
                a0 = fmaf(v.x, wreg[c].x, a0);
                a1 = fmaf(v.y, wreg[c].y, a1);
                a2 = fmaf(v.z, wreg[c].z, a2);
                a3 = fmaf(v.w, wreg[c].w, a3);
            }
            float acc = (a0 + a1) + (a2 + a3);
            float other = __shfl_xor(acc, 32);    // partner lane shares d
            if (half == 0) {
                float nfv = nf[un];
                float deg = (nfv > 0.f) ? (1.f / nfv) : 0.f;
                wzux[(size_t)un * D + d] = nfv * (acc + deg * (other + ub));
            }
        }
    }
}

// ---------------- Quarter-bucket sort + register agg + fused output --------
// One block per 64 nodes. Filter bucket records on top-2 local bits,
// counting-sort into LDS, one wave per node accumulates newz in registers,
// then the fused epilogue computes out = (1-A)*z - A*(newz@W) directly.
__global__ __launch_bounds__(256) void bucket_sort_agg_kernel(
    const float4* __restrict__ wzux4,
    const int* __restrict__ gcur, const int* __restrict__ data,
    const int* __restrict__ ovf_cnt, const int2* __restrict__ ovf,
    const float* __restrict__ nf,
    const float4* __restrict__ gamma4, const float4* __restrict__ beta4,
    const float* __restrict__ z, const float* __restrict__ W,
    float* __restrict__ out, int N)
{
    __shared__ int sorted[CAPQ];
    __shared__ int offs[65];
    __shared__ int curs[64];
    __shared__ float4 rowbuf[4][17];   // per-wave newz row slot

    const int blk    = blockIdx.x;       // 64-node group
    const int base   = blk << 6;
    const int cntN   = min(64, N - base);
    const int bucket = blk >> 2;
    const int q      = blk & 3;
    const int t      = threadIdx.x;
    const int lane   = t & 63;
    const int wid    = t >> 6;

    // lane-private W column: wcol[k] = W[k][lane]
    float wcol[D];
#pragma unroll
    for (int k = 0; k < D; ++k) wcol[k] = W[k * D + lane];

    if (t < 65) offs[t] = 0;
    __syncthreads();

    const int ocnt = min(*ovf_cnt, OVF_CAP);

    // count (filtered by quarter)
    for (int sub = 0; sub < NSUB; ++sub) {
        const int cs = min(gcur[bucket * NSUB + sub], CAPS);
        const int* p = &data[(bucket * NSUB + sub) * CAPS];
        for (int i = t; i < cs; i += 256) {
            int l8 = (p[i] >> 1) & (GBN - 1);
            if ((l8 >> 6) == q) atomicAdd(&offs[(l8 & 63) + 1], 1);
        }
    }
    for (int i = t; i < ocnt; i += 256) {
        int2 v = ovf[i];
        int l8 = (v.y >> 1) & (GBN - 1);
        if (v.x == bucket && (l8 >> 6) == q) atomicAdd(&offs[(l8 & 63) + 1], 1);
    }
    __syncthreads();

    // inclusive scan of offs[1..64] by wave 0
    if (t < 64) {
        int v = offs[t + 1];
#pragma unroll
        for (int off = 1; off < 64; off <<= 1) {
            int u = __shfl_up(v, off);
            if (t >= off) v += u;
        }
        offs[t + 1] = v;
    }
    __syncthreads();
    if (t < 64) curs[t] = offs[t];
    __syncthreads();

    // place
    for (int sub = 0; sub < NSUB; ++sub) {
        const int cs = min(gcur[bucket * NSUB + sub], CAPS);
        const int* p = &data[(bucket * NSUB + sub) * CAPS];
        for (int i = t; i < cs; i += 256) {
            int rec = p[i];
            int l8 = (rec >> 1) & (GBN - 1);
            if ((l8 >> 6) == q) {
                int pos = atomicAdd(&curs[l8 & 63], 1);
                if (pos < CAPQ) sorted[pos] = rec;
            }
        }
    }
    for (int i = t; i < ocnt; i += 256) {
        int2 v = ovf[i];
        int l8 = (v.y >> 1) & (GBN - 1);
        if (v.x == bucket && (l8 >> 6) == q) {
            int pos = atomicAdd(&curs[l8 & 63], 1);
            if (pos < CAPQ) sorted[pos] = v.y;
        }
    }
    __syncthreads();

    // register aggregation: wave wid handles locals wid, wid+4, ...
    const int g = lane >> 4;      // edge slot within wave
    const int l = lane & 15;      // float4 slot within row
    const float4 gm = gamma4[l];
    const float4 bt = beta4[l];

    for (int local = wid; local < cntN; local += 4) {
        const int s = min(offs[local], CAPQ);
        const int e = min(offs[local + 1], CAPQ);
        const int n = base + local;
        const float4 self = wzux4[n * 16 + l];
        float4 acc = make_float4(0.f, 0.f, 0.f, 0.f);

#define PROC2(ENT, OROW)                                                     \
        {                                                                    \
            int ent = (ENT);                                                 \
            float sgn = (ent & 1) ? -1.f : 1.f;                              \
            float4 o = (OROW);                                               \
            float r0 = fmaxf(sgn * (self.x - o.x), 0.f);                     \
            float r1 = fmaxf(sgn * (self.y - o.y), 0.f);                     \
            float r2 = fmaxf(sgn * (self.z - o.z), 0.f);                     \
            float r3 = fmaxf(sgn * (self.w - o.w), 0.f);                     \
            float ss = r0 + r1 + r2 + r3;                                    \
            float sq = r0 * r0 + r1 * r1 + r2 * r2 + r3 * r3;                \
            _Pragma("unroll")                                                \
            for (int off = 1; off < 16; off <<= 1) {                         \
                ss += __shfl_xor(ss, off);                                   \
                sq += __shfl_xor(sq, off);                                   \
            }                                                                \
            float mu   = ss * (1.f / 64.f);                                  \
            float var  = sq * (1.f / 64.f) - mu * mu;                        \
            float rstd = rsqrtf(var + LN_EPS);                               \
            acc.x += sgn * ((r0 - mu) * rstd * gm.x + bt.x);                 \
            acc.y += sgn * ((r1 - mu) * rstd * gm.y + bt.y);                 \
            acc.z += sgn * ((r2 - mu) * rstd * gm.z + bt.z);                 \
            acc.w += sgn * ((r3 - mu) * rstd * gm.w + bt.w);                 \
        }

        int i = s + g;
        for (; i + 4 < e; i += 8) {
            int ea = sorted[i];
            int eb = sorted[i + 4];
            float4 oa = wzux4[(ea >> 9) * 16 + l];
            float4 ob = wzux4[(eb >> 9) * 16 + l];
            PROC2(ea, oa);
            PROC2(eb, ob);
        }
        if (i < e) {
            int ea = sorted[i];
            float4 oa = wzux4[(ea >> 9) * 16 + l];
            PROC2(ea, oa);
        }
#undef PROC2

        // butterfly across the 4 edge slots (allreduce)
#pragma unroll
        for (int m = 16; m < 64; m <<= 1) {
            acc.x += __shfl_xor(acc.x, m);
            acc.y += __shfl_xor(acc.y, m);
            acc.z += __shfl_xor(acc.z, m);
            acc.w += __shfl_xor(acc.w, m);
        }

        // fused output: out = (1-A)*z - A*(nf[n]*acc @ W)
        float nfv = nf[n];
        if (g == 0) {
            rowbuf[wid][l] = make_float4(acc.x * nfv, acc.y * nfv,
                                         acc.z * nfv, acc.w * nfv);
        }
        // wave-private LDS write->read; compiler inserts the lgkm wait
        float m0 = 0.f, m1 = 0.f, m2 = 0.f, m3 = 0.f;
#pragma unroll
        for (int c = 0; c < 16; ++c) {
            float4 rv = rowbuf[wid][c];
            m0 = fmaf(rv.x, wcol[c * 4 + 0], m0);
            m1 = fmaf(rv.y, wcol[c * 4 + 1], m1);
            m2 = fmaf(rv.z, wcol[c * 4 + 2], m2);
            m3 = fmaf(rv.w, wcol[c * 4 + 3], m3);
        }
        out[(size_t)n * D + lane] =
            (1.0f - ALPHA) * z[(size_t)n * D + lane]
            - ALPHA * ((m0 + m1) + (m2 + m3));
    }
}

extern "C" void kernel_launch(void* const* d_in, const int* in_sizes, int n_in,
                              void* d_out, int out_size, void* d_ws, size_t ws_size,
                              hipStream_t stream) {
    const float* z     = (const float*)d_in[0];
    const float* x     = (const float*)d_in[1];
    const int*   ei    = (const int*)d_in[2];
    const float* nf    = (const float*)d_in[3];
    const float* W     = (const float*)d_in[4];
    const float* Uw    = (const float*)d_in[5];
    const float* Ub    = (const float*)d_in[6];
    const float* gamma = (const float*)d_in[7];
    const float* beta  = (const float*)d_in[8];

    const int N = in_sizes[0] / D;      // 100000
    const int E = in_sizes[2] / 2;      // 1200000
    const int nbuck = (N + GBN - 1) >> GSH;          // 391
    const int sb = (E + TILE - 1) / TILE;            // 586 scatter blocks

    float* out = (float*)d_out;

    // ---- workspace layout ----
    char* ws = (char*)d_ws;
    size_t off = 0;
    auto alloc = [&](size_t bytes) {
        char* p = ws + off;
        off += (bytes + 255) & ~(size_t)255;
        return p;
    };
    float* wzux    = (float*)alloc((size_t)N * D * sizeof(float));              // 25.6 MB
    int*   gcur    = (int*)  alloc((size_t)nbuck * NSUB * sizeof(int));         // 12.5 KB
    int*   ovf_cnt = (int*)  alloc(sizeof(int));
    int*   data    = (int*)  alloc((size_t)nbuck * NSUB * CAPS * sizeof(int));  // 16 MB
    int2*  ovf     = (int2*) alloc((size_t)OVF_CAP * sizeof(int2));             // 1 MB

    hipMemsetAsync(gcur, 0, (size_t)nbuck * NSUB * sizeof(int), stream);
    hipMemsetAsync(ovf_cnt, 0, sizeof(int), stream);

    front_kernel<<<sb + WZB, 256, 0, stream>>>(
        ei, ei + E, gcur, data, ovf_cnt, ovf, E, nbuck, sb,
        z, x, nf, W, Uw, Ub, wzux, N);

    int ab = (N + 63) / 64;
    bucket_sort_agg_kernel<<<ab, 256, 0, stream>>>(
        (const float4*)wzux, gcur, data, ovf_cnt, ovf, nf,
        (const float4*)gamma, (const float4*)beta,
        z, W, out, N);
}